// Round 3
// baseline (4967.268 us; speedup 1.0000x reference)
//
#include <hip/hip_runtime.h>

#define B_  128
#define T_  4096
#define F_  64
#define H_  128
#define NT  512
#define PART_STRIDE 516   // dwords per partial-slice row (516*4 % 16 == 0, %32 banks = 4)

typedef _Float16 half2_t __attribute__((ext_vector_type(2)));
typedef _Float16 half8_t __attribute__((ext_vector_type(8)));

#if __has_builtin(__builtin_amdgcn_fdot2)
__device__ __forceinline__ float fdot2(half2_t a, half2_t b, float c) {
  return __builtin_amdgcn_fdot2(a, b, c, false);
}
#else
__device__ __forceinline__ float fdot2(half2_t a, half2_t b, float c) {
  return c + (float)a[0] * (float)b[0] + (float)a[1] * (float)b[1];
}
#endif

__device__ __forceinline__ half2_t pack2(float a, float b) {
  half2_t r; r[0] = (_Float16)a; r[1] = (_Float16)b; return r;
}

// quad-broadcast lane (base|Q) -> all 4 lanes of the quad, via DPP (VALU pipe, no LDS)
template<int Q>
__device__ __forceinline__ float qbcast(float v) {
  return __int_as_float(__builtin_amdgcn_update_dpp(
      0, __float_as_int(v), Q * 0x55 /*quad_perm all->Q*/, 0xF, 0xF, true));
}

__device__ __forceinline__ float fast_tanh(float x) {
  float e = __builtin_amdgcn_exp2f(x * -2.8853900817779268f);
  return 2.0f * __builtin_amdgcn_rcpf(1.0f + e) - 1.0f;
}

// Two sequences per block: W registers shared, independent instruction streams
// per seq fill each other's LDS/dot latency; one barrier pair serves two steps.
__global__ __launch_bounds__(512, 2) void lstm_2seq_kernel(
    const float* __restrict__ X,    // [B, T, F]
    const float* __restrict__ Wih,  // [4H, F]
    const float* __restrict__ Whh,  // [4H, H]
    const float* __restrict__ bih,  // [4H]
    const float* __restrict__ bhh,  // [4H]
    float* __restrict__ out)        // [B, H]
{
  const int tid  = threadIdx.x;
  const int b2   = blockIdx.x;          // sequence pair
  const int lane = tid & 63;
  const int w    = tid >> 6;            // wave 0..7
  const int s    = w >> 1;              // k-slice 0..3  (k in [48s, 48s+48))
  const int hw   = w & 1;               // column half
  const int col  = 64 * hw + lane;      // writer-side column 0..127

  // [seq][buf][..]: k operand vector [h(128 f16) | x(64 f16)] = 96 half2
  __shared__ __align__(16) half2_t kbuf[2][2][96];
  __shared__ __align__(16) float   part[2][4][PART_STRIDE];

  // ---- prologue: this thread's 4 W-row slices (shared across both seqs)
  half2_t Wr[4][24];   // 96 VGPRs
  const int k0 = 48 * s;
#pragma unroll
  for (int r = 0; r < 4; ++r) {
    const int g = r * 128 + col;
#pragma unroll
    for (int j = 0; j < 24; ++j) {
      const int k = k0 + 2 * j;
      float2 wv;
      if (k < 128) wv = *(const float2*)(Whh + (size_t)g * H_ + k);
      else         wv = *(const float2*)(Wih + (size_t)g * F_ + (k - 128));
      Wr[r][j] = pack2(wv.x, wv.y);
    }
  }
  float bias_r[4];
#pragma unroll
  for (int r = 0; r < 4; ++r) {
    const int g = r * 128 + col;
    bias_r[r] = (s == 0) ? (bih[g] + bhh[g]) : 0.0f;
  }

  // ---- reduce-side constants: thread tid owns gate (tid&3)*128 + (tid>>2)
  const int  rcol = tid >> 2;
  const bool is_g = ((tid & 3) == 2);
  const float AK1 = is_g ? -2.8853900817779268f : -1.4426950408889634f;
  const float AK2 = is_g ? 2.0f : 1.0f;
  const float AK3 = is_g ? -1.0f : 0.0f;

  // ---- init h0 = 0 for both seqs
  if (tid < H_) {
    ((_Float16*)&kbuf[0][0][0])[tid] = (_Float16)0.0f;
    ((_Float16*)&kbuf[1][0][0])[tid] = (_Float16)0.0f;
  }

  // ---- x staging: wave 7; lanes 0..31 -> seq 0, lanes 32..63 -> seq 1
  const bool   xloader = (w == 7);
  const int    xq_seq  = lane >> 5;     // which seq this lane stages
  const int    l2      = lane & 31;
  const float* xbase   = X + ((size_t)(2 * b2 + xq_seq)) * T_ * F_;
  float2 xq0, xq1;
  if (xloader) {
    float2 a0 = ((const float2*)(xbase + 0 * F_))[l2];
    kbuf[xq_seq][0][64 + l2] = pack2(a0.x, a0.y);    // x[0] -> buf 0
    xq0 = ((const float2*)(xbase + 1 * F_))[l2];     // holds x[1]
    xq1 = ((const float2*)(xbase + 2 * F_))[l2];     // holds x[2]
  }

  float c_state[2] = {0.0f, 0.0f};
  float h_last[2]  = {0.0f, 0.0f};

  __syncthreads();

#pragma unroll 2
  for (int t = 0; t < T_; ++t) {
    const int buf = t & 1;

    // ---- dot phase, both sequences (independent streams -> ILP)
#pragma unroll
    for (int q = 0; q < 2; ++q) {
      union H8 { half8_t v8; half2_t h2[4]; };
      H8 kv[6];
      const half8_t* kp = (const half8_t*)&kbuf[q][buf][24 * s];
#pragma unroll
      for (int u = 0; u < 6; ++u) kv[u].v8 = kp[u];

      float acc0 = bias_r[0], acc1 = bias_r[1], acc2 = bias_r[2], acc3 = bias_r[3];
#pragma unroll
      for (int u = 0; u < 6; ++u) {
#pragma unroll
        for (int m = 0; m < 4; ++m) {
          const half2_t kk = kv[u].h2[m];
          const int j = u * 4 + m;
          acc0 = fdot2(Wr[0][j], kk, acc0);
          acc1 = fdot2(Wr[1][j], kk, acc1);
          acc2 = fdot2(Wr[2][j], kk, acc2);
          acc3 = fdot2(Wr[3][j], kk, acc3);
        }
      }
      float4 pw; pw.x = acc0; pw.y = acc1; pw.z = acc2; pw.w = acc3;
      *(float4*)&part[q][s][4 * col] = pw;
    }

    __syncthreads();   // B1: partials (both seqs) visible

    // ---- reduce + activation + c/h update, both sequences
#pragma unroll
    for (int q = 0; q < 2; ++q) {
      float pre = (part[q][0][tid] + part[q][1][tid]) +
                  (part[q][2][tid] + part[q][3][tid]);
      float e   = __builtin_amdgcn_exp2f(pre * AK1);
      float act = AK2 * __builtin_amdgcn_rcpf(1.0f + e) + AK3;  // sigmoid / tanh(g)

      float ai = qbcast<0>(act);
      float af = qbcast<1>(act);
      float ag = qbcast<2>(act);
      float ao = qbcast<3>(act);

      c_state[q] = af * c_state[q] + ai * ag;
      float hn = ao * fast_tanh(c_state[q]);
      h_last[q] = hn;

      if ((tid & 3) == 0)
        ((_Float16*)&kbuf[q][buf ^ 1][0])[rcol] = (_Float16)hn;
    }

    // ---- x[t+1] staging + prefetch x[t+3] (each lane serves its seq)
    if (xloader) {
      int nu = t + 3; nu = (nu < T_) ? nu : (T_ - 1);
      const float2* xrn = (const float2*)(xbase + (size_t)nu * F_);
      if ((t & 1) == 0) {            // static under unroll-2
        kbuf[xq_seq][buf ^ 1][64 + l2] = pack2(xq0.x, xq0.y);   // x[t+1]
        xq0 = xrn[l2];
      } else {
        kbuf[xq_seq][buf ^ 1][64 + l2] = pack2(xq1.x, xq1.y);
        xq1 = xrn[l2];
      }
    }

    __syncthreads();   // B2: next h/x visible; part safe to rewrite
  }

  if ((tid & 3) == 0) {
    out[((size_t)(2 * b2 + 0)) * H_ + rcol] = h_last[0];
    out[((size_t)(2 * b2 + 1)) * H_ + rcol] = h_last[1];
  }
}

extern "C" void kernel_launch(void* const* d_in, const int* in_sizes, int n_in,
                              void* d_out, int out_size, void* d_ws, size_t ws_size,
                              hipStream_t stream) {
  const float* X   = (const float*)d_in[0];
  const float* Wih = (const float*)d_in[1];
  const float* Whh = (const float*)d_in[2];
  const float* bih = (const float*)d_in[3];
  const float* bhh = (const float*)d_in[4];
  float* out = (float*)d_out;

  lstm_2seq_kernel<<<dim3(B_ / 2), dim3(NT), 0, stream>>>(X, Wih, Whh, bih, bhh, out);
}

// Round 4
// 2480.914 us; speedup vs baseline: 2.0022x; 2.0022x over previous
//
#include <hip/hip_runtime.h>

#define B_  128
#define T_  4096
#define F_  64
#define H_  128
#define NT  512

typedef _Float16 half8_t __attribute__((ext_vector_type(8)));
typedef _Float16 half2_t __attribute__((ext_vector_type(2)));
typedef float    f32x4   __attribute__((ext_vector_type(4)));

__device__ __forceinline__ half2_t pack2(float a, float b) {
  half2_t r; r[0] = (_Float16)a; r[1] = (_Float16)b; return r;
}

// One barrier/step. __syncthreads() would emit s_waitcnt vmcnt(0) and drain the
// in-flight x prefetch; we only need LDS ordering -> lgkmcnt(0) + s_barrier.
__device__ __forceinline__ void wg_barrier() {
  __asm__ volatile("s_waitcnt lgkmcnt(0)\n\ts_barrier" ::: "memory");
}

__device__ __forceinline__ float fast_sigmoid(float x) {
  float e = __builtin_amdgcn_exp2f(x * -1.4426950408889634f);
  return __builtin_amdgcn_rcpf(1.0f + e);
}
__device__ __forceinline__ float fast_tanh(float x) {
  float e = __builtin_amdgcn_exp2f(x * -2.8853900817779268f);
  return 2.0f * __builtin_amdgcn_rcpf(1.0f + e) - 1.0f;
}

// One sequence per block. Per step: gates[1x512] = [1x192] @ [192x512] via
// mfma_f32_16x16x32_f16 with M=1 (rows 1..15 garbage-tolerant; A-frag reads are
// 16-lane broadcasts so all rows carry identical finite data).
// Wave w owns cols 16w..16w+15 of ALL FOUR gates -> i,f,g,o of a column land in
// the same lane (reg0, lanes 0..15): in-register c/h update, 1 barrier/step.
__global__ __launch_bounds__(NT, 2) void lstm_mfma_kernel(
    const float* __restrict__ X,    // [B, T, F]
    const float* __restrict__ Wih,  // [4H, F]
    const float* __restrict__ Whh,  // [4H, H]
    const float* __restrict__ bih,  // [4H]
    const float* __restrict__ bhh,  // [4H]
    float* __restrict__ out)        // [B, H]
{
  const int tid  = threadIdx.x;
  const int b    = blockIdx.x;
  const int lane = tid & 63;
  const int w    = tid >> 6;     // wave 0..7: cols 16w..16w+15 of each gate
  const int lg   = lane >> 4;    // k-window group 0..3
  const int lc   = lane & 15;    // column-within-16

  __shared__ __align__(16) _Float16 hbuf[2][H_];   // h ring (f16), 2 x 256 B
  __shared__ __align__(16) _Float16 xbuf[4][F_];   // x ring (f16), 4 x 128 B

  // ---- B-operand fragments: Wf[g][c]; lane holds B[k=8lg+j][n=lc] of K-tile c,
  // i.e. W[128g + 16w + lc][32c + 8lg + j], j=0..7  (f32 -> f16)
  half8_t Wf[4][6];
  float   bias_g[4];
#pragma unroll
  for (int g = 0; g < 4; ++g) {
    const int row = 128 * g + 16 * w + lc;
    bias_g[g] = bih[row] + bhh[row];
#pragma unroll
    for (int c = 0; c < 6; ++c) {
      const float* src = (c < 4) ? (Whh + (size_t)row * H_ + 32 * c + 8 * lg)
                                 : (Wih + (size_t)row * F_ + 32 * (c - 4) + 8 * lg);
      float4 lo = *(const float4*)(src);
      float4 hi = *(const float4*)(src + 4);
      half8_t v;
      v[0] = (_Float16)lo.x; v[1] = (_Float16)lo.y;
      v[2] = (_Float16)lo.z; v[3] = (_Float16)lo.w;
      v[4] = (_Float16)hi.x; v[5] = (_Float16)hi.y;
      v[6] = (_Float16)hi.z; v[7] = (_Float16)hi.w;
      Wf[g][c] = v;
    }
  }

  // h0 = 0
  if (tid < H_) hbuf[0][tid] = (_Float16)0.0f;

  // ---- x stager: wave 7 lanes 0..31; slot u%4 holds x[u] as f16
  const bool   stager = (w == 7) && (lane < 32);
  const float* xbase  = X + (size_t)b * T_ * F_;
  float2 xq0, xq1;
  if (stager) {
    float2 a0 = ((const float2*)(xbase + 0 * F_))[lane];
    float2 a1 = ((const float2*)(xbase + 1 * F_))[lane];
    *(half2_t*)&xbuf[0][2 * lane] = pack2(a0.x, a0.y);
    *(half2_t*)&xbuf[1][2 * lane] = pack2(a1.x, a1.y);
    xq0 = ((const float2*)(xbase + 2 * F_))[lane];   // x[2]
    xq1 = ((const float2*)(xbase + 3 * F_))[lane];   // x[3]
  }

  float c_state = 0.0f, h_last = 0.0f;

  wg_barrier();

#pragma unroll 2
  for (int t = 0; t < T_; ++t) {
    const int buf  = t & 1;
    const int slot = t & 3;

    // ---- A-frags: broadcast b128 reads (16 lanes/address -> conflict-free)
    half8_t Af[6];
#pragma unroll
    for (int c = 0; c < 4; ++c)
      Af[c] = *(const half8_t*)&hbuf[buf][32 * c + 8 * lg];
#pragma unroll
    for (int c = 0; c < 2; ++c)
      Af[4 + c] = *(const half8_t*)&xbuf[slot][32 * c + 8 * lg];

    // ---- 24 mfma: 4 independent accumulator chains (one per gate)
    f32x4 z = {0.0f, 0.0f, 0.0f, 0.0f};
    f32x4 acc0 = z, acc1 = z, acc2 = z, acc3 = z;
#pragma unroll
    for (int c = 0; c < 6; ++c) {
      acc0 = __builtin_amdgcn_mfma_f32_16x16x32_f16(Af[c], Wf[0][c], acc0, 0, 0, 0);
      acc1 = __builtin_amdgcn_mfma_f32_16x16x32_f16(Af[c], Wf[1][c], acc1, 0, 0, 0);
      acc2 = __builtin_amdgcn_mfma_f32_16x16x32_f16(Af[c], Wf[2][c], acc2, 0, 0, 0);
      acc3 = __builtin_amdgcn_mfma_f32_16x16x32_f16(Af[c], Wf[3][c], acc3, 0, 0, 0);
    }

    // ---- x staging: write x[t+2] -> slot (t+2)&3, issue load of x[t+4]
    if (stager) {
      int nu = t + 4; nu = (nu < T_) ? nu : (T_ - 1);
      const float2* xrn = (const float2*)(xbase + (size_t)nu * F_);
      if ((t & 1) == 0) {        // static under unroll-2
        *(half2_t*)&xbuf[(t + 2) & 3][2 * lane] = pack2(xq0.x, xq0.y);
        xq0 = xrn[lane];
      } else {
        *(half2_t*)&xbuf[(t + 2) & 3][2 * lane] = pack2(xq1.x, xq1.y);
        xq1 = xrn[lane];
      }
    }

    // ---- gate activation + c/h update (row 0 == reg 0; all rows identical,
    // so every lane computes the true value for its column lc)
    float si = fast_sigmoid(acc0[0] + bias_g[0]);
    float sf = fast_sigmoid(acc1[0] + bias_g[1]);
    float sg = fast_tanh   (acc2[0] + bias_g[2]);
    float so = fast_sigmoid(acc3[0] + bias_g[3]);

    c_state = sf * c_state + si * sg;
    float hn = so * fast_tanh(c_state);
    h_last = hn;

    if (lane < 16) hbuf[buf ^ 1][16 * w + lc] = (_Float16)hn;

    wg_barrier();
  }

  if (lane < 16) out[(size_t)b * H_ + 16 * w + lc] = h_last;
}

extern "C" void kernel_launch(void* const* d_in, const int* in_sizes, int n_in,
                              void* d_out, int out_size, void* d_ws, size_t ws_size,
                              hipStream_t stream) {
  const float* X   = (const float*)d_in[0];
  const float* Wih = (const float*)d_in[1];
  const float* Whh = (const float*)d_in[2];
  const float* bih = (const float*)d_in[3];
  const float* bhh = (const float*)d_in[4];
  float* out = (float*)d_out;

  lstm_mfma_kernel<<<dim3(B_), dim3(NT), 0, stream>>>(X, Wih, Whh, bih, bhh, out);
}